// Round 1
// baseline (387.946 us; speedup 1.0000x reference)
//
#include <hip/hip_runtime.h>
#include <math.h>

// Sizes (fixed by the reference)
#define BATCH 16384
#define K_DIM 3072
#define NOUT  128      // E * (L2+1) = 8*16
#define NEXP  8

typedef float  f32x4  __attribute__((ext_vector_type(4)));
typedef __bf16 bf16x8 __attribute__((ext_vector_type(8)));
typedef unsigned int u32x4 __attribute__((ext_vector_type(4)));
typedef unsigned int u32x2 __attribute__((ext_vector_type(2)));

__device__ __forceinline__ unsigned short f2bf(float f) {
  union { float f; unsigned u; } v; v.f = f;
  unsigned u = v.u + 0x7fffu + ((v.u >> 16) & 1u);   // RNE
  return (unsigned short)(u >> 16);
}

__device__ __forceinline__ bf16x8 asbf(u32x4 v) {
  union { u32x4 u; bf16x8 b; } c; c.u = v; return c.b;
}

// fp32x8 -> bf16x8, RNE (compiler lowers to v_cvt_pk_bf16_f32 on gfx950)
__device__ __forceinline__ bf16x8 cvt8(f32x4 lo, f32x4 hi) {
  bf16x8 r;
  r[0] = (__bf16)lo[0]; r[1] = (__bf16)lo[1]; r[2] = (__bf16)lo[2]; r[3] = (__bf16)lo[3];
  r[4] = (__bf16)hi[0]; r[5] = (__bf16)hi[1]; r[6] = (__bf16)hi[2]; r[7] = (__bf16)hi[3];
  return r;
}

// ---------------- kernel 1: w1 fp32 -> bf16 (128*3072 elements) + accs zero ----------------
__global__ void cvt_w1_kernel(const float* __restrict__ w1, unsigned short* __restrict__ o,
                              float* __restrict__ accs) {
  if (blockIdx.x == 0 && threadIdx.x < 16) accs[threadIdx.x] = 0.f;
  int i = blockIdx.x * 256 + threadIdx.x;          // 98304 float4s
  f32x4 v = ((const f32x4*)w1)[i];
  u32x2 p = { (unsigned)f2bf(v.x) | ((unsigned)f2bf(v.y) << 16),
              (unsigned)f2bf(v.z) | ((unsigned)f2bf(v.w) << 16) };
  ((u32x2*)o)[i] = p;
}

// ---------------- kernel 2: fused router + GEMM + MoE epilogue ----------------
// BM=32 rows/block, all 128 outputs, BK=64/iter. 512 blocks x 256 threads.
// K-loop is barrier-free: A (x) and B (w1bf, L2-resident) stream straight into
// registers with a 2-deep double buffer; no LDS in the hot loop.
__global__ __launch_bounds__(256, 2) void moe_main_kernel(
    const float* __restrict__ x, const unsigned short* __restrict__ w1bf,
    const float* __restrict__ b1, const float* __restrict__ w2,
    const float* __restrict__ b2, const float* __restrict__ w3,
    const float* __restrict__ b3, const float* __restrict__ psqt,
    const float* __restrict__ st, const float* __restrict__ rw,
    const float* __restrict__ rb, float* __restrict__ out,
    float* __restrict__ accs) {
  __shared__ __align__(16) float Cl[32 * 132];      // 16896 B (C scratch, pad 132)
  __shared__ __align__(16) float w2s[8 * 964];      // 30848 B, i-major, padded
  __shared__ float b1s[128], b2s[256], w3s[256], b3s[8];
  __shared__ float rws[8 * 65];                     // router weights, pad 65 (bank-free)
  __shared__ float wred[4], zred[4];
  __shared__ int   hist[8];

  const int tid = threadIdx.x;
  const int bm  = blockIdx.x;

  // ---- stage epilogue/router constants (w2 transposed to [e][i*32+o]) ----
  for (int i = tid; i < 7680; i += 256) {
    int e = i / 960; int r = i - e * 960; int o = r / 30; int ii = r - o * 30;
    w2s[e * 964 + ii * 32 + o] = w2[i];
  }
  for (int i = tid; i < 512; i += 256) rws[(i >> 6) * 65 + (i & 63)] = rw[i];
  if (tid < 128) b1s[tid] = b1[tid];
  b2s[tid] = b2[tid];
  w3s[tid] = w3[tid];
  if (tid < 8) { b3s[tid] = b3[tid]; hist[tid] = 0; }
  __syncthreads();

  // ---- wave/lane geometry ----
  const int lane = tid & 63, wv = tid >> 6;
  const int l16 = lane & 15, lq = lane >> 4;
  const int rt = wv & 1;              // row-tile (16 rows)
  const int cb = (wv >> 1) * 4;       // first of 4 col-tiles

  const float*          pA = x    + (size_t)(bm * 32 + rt * 16 + l16) * K_DIM + lq * 8;
  const unsigned short* pB = w1bf + (size_t)(cb * 16 + l16) * K_DIM + lq * 8;

  f32x4 aR[2][4];   // A double buffer (fp32, pre-convert)
  u32x4 bR[2][8];   // B double buffer (bf16 bits), [c*2+ks]

#define LOADT(S, KT) do {                                        \
    const float* pa_ = pA + (KT) * 64;                           \
    aR[S][0] = *(const f32x4*)(pa_);                             \
    aR[S][1] = *(const f32x4*)(pa_ + 4);                         \
    aR[S][2] = *(const f32x4*)(pa_ + 32);                        \
    aR[S][3] = *(const f32x4*)(pa_ + 36);                        \
    const unsigned short* pb_ = pB + (KT) * 64;                  \
    bR[S][0] = *(const u32x4*)(pb_);                             \
    bR[S][1] = *(const u32x4*)(pb_ + 32);                        \
    bR[S][2] = *(const u32x4*)(pb_ + 16 * K_DIM);                \
    bR[S][3] = *(const u32x4*)(pb_ + 16 * K_DIM + 32);           \
    bR[S][4] = *(const u32x4*)(pb_ + 32 * K_DIM);                \
    bR[S][5] = *(const u32x4*)(pb_ + 32 * K_DIM + 32);           \
    bR[S][6] = *(const u32x4*)(pb_ + 48 * K_DIM);                \
    bR[S][7] = *(const u32x4*)(pb_ + 48 * K_DIM + 32);           \
  } while (0)

#define COMPUTE(S) do {                                                              \
    bf16x8 af0 = cvt8(aR[S][0], aR[S][1]);                                           \
    bf16x8 af1 = cvt8(aR[S][2], aR[S][3]);                                           \
    _Pragma("unroll")                                                                \
    for (int c = 0; c < 4; ++c)                                                      \
      acc[c] = __builtin_amdgcn_mfma_f32_16x16x32_bf16(af0, asbf(bR[S][c * 2 + 0]),  \
                                                       acc[c], 0, 0, 0);             \
    _Pragma("unroll")                                                                \
    for (int c = 0; c < 4; ++c)                                                      \
      acc[c] = __builtin_amdgcn_mfma_f32_16x16x32_bf16(af1, asbf(bR[S][c * 2 + 1]),  \
                                                       acc[c], 0, 0, 0);             \
  } while (0)

  // issue kt=0 loads now; they fly while the router math runs
  LOADT(0, 0);

  // ---- inline router: thread = (row bl, expert e), fp64 for argmax parity ----
  const int bl = tid >> 3, e = tid & 7;
  const int bg = bm * 32 + bl;
  const float* xrow = x + (size_t)bg * K_DIM;
  double lr = (double)rb[e];
#pragma unroll
  for (int c = 0; c < 32; ++c)
    lr = fma((double)xrow[c], (double)rws[e * 65 + c], lr);
#pragma unroll
  for (int c = 0; c < 32; ++c)
    lr = fma((double)xrow[1536 + c], (double)rws[e * 65 + 32 + c], lr);

  // argmax over the 8 expert lanes (first-max-wins, jnp.argmax semantics)
  double mx = lr; int mi = e;
#pragma unroll
  for (int m = 1; m < 8; m <<= 1) {
    double ov = __shfl_xor(mx, m);
    int    oi = __shfl_xor(mi, m);
    if (ov > mx || (ov == mx && oi < mi)) { mx = ov; mi = oi; }
  }
  double ssum = exp(lr - mx);
#pragma unroll
  for (int m = 1; m < 8; m <<= 1) ssum += __shfl_xor(ssum, m);
  const double lse = mx + log(ssum);
  const float  logp_self = (float)(lr - lse);
  const int    rowEidx   = mi;

  if (e == 0) atomicAdd(&hist[rowEidx], 1);
  float zc = (e == 0) ? (float)(lse * lse) : 0.f;
#pragma unroll
  for (int m = 1; m < 64; m <<= 1) zc += __shfl_xor(zc, m);
  if (lane == 0) zred[wv] = zc;

  // ---- barrier-free K-loop (48 steps of K=64), register double-buffered ----
  f32x4 acc[4];
#pragma unroll
  for (int c = 0; c < 4; ++c) acc[c] = (f32x4){0.f, 0.f, 0.f, 0.f};

#pragma unroll 1
  for (int kt = 0; kt < 48; kt += 2) {
    LOADT(1, kt + 1);
    COMPUTE(0);
    if (kt + 2 < 48) LOADT(0, kt + 2);
    COMPUTE(1);
  }

  // ---- C -> LDS, then epilogue ----
#pragma unroll
  for (int c = 0; c < 4; ++c)
#pragma unroll
    for (int r = 0; r < 4; ++r)
      Cl[(rt * 16 + lq * 4 + r) * 132 + (cb + c) * 16 + l16] = acc[c][r];
  __syncthreads();

  // ---------------- epilogue: one thread per (sample, expert) ----------------
  float a[16];
#pragma unroll
  for (int j = 0; j < 16; ++j) a[j] = Cl[bl * 132 + e * 16 + j] + b1s[e * 16 + j];

  float h[30];
#pragma unroll
  for (int j = 0; j < 15; ++j) {
    float v = a[j];
    h[j]      = fminf(fmaxf(v * v * (255.0f / 256.0f), 0.f), 1.f);
    h[15 + j] = fminf(fmaxf(v, 0.f), 1.f);
  }

  float acc2[32];
#pragma unroll
  for (int o = 0; o < 32; ++o) acc2[o] = b2s[e * 32 + o];
  const f32x4* wrow = (const f32x4*)&w2s[e * 964];
#pragma unroll
  for (int i = 0; i < 30; ++i) {
    float hv = h[i];
#pragma unroll
    for (int o4 = 0; o4 < 8; ++o4) {
      f32x4 wq = wrow[i * 8 + o4];
      acc2[o4 * 4 + 0] += hv * wq.x;
      acc2[o4 * 4 + 1] += hv * wq.y;
      acc2[o4 * 4 + 2] += hv * wq.z;
      acc2[o4 * 4 + 3] += hv * wq.w;
    }
  }

  float outv = b3s[e] + a[15];  // b3 + skip
#pragma unroll
  for (int o = 0; o < 32; ++o) {
    float l2v = fminf(fmaxf(acc2[o], 0.f), 1.f);
    outv += l2v * w3s[e * 32 + o];
  }

  // probe softmax over the 8 experts (lanes e=0..7 within each group of 8)
  float eo  = (outv + psqt[bg]) * 600.0f;
  float dd  = eo - st[bg];
  float err = dd * dd;
  float mn = err;
  mn = fminf(mn, __shfl_xor(mn, 1));
  mn = fminf(mn, __shfl_xor(mn, 2));
  mn = fminf(mn, __shfl_xor(mn, 4));
  float wexp = expf(-(err - mn));
  float ss = wexp;
  ss += __shfl_xor(ss, 1); ss += __shfl_xor(ss, 2); ss += __shfl_xor(ss, 4);
  float pt  = wexp / ss;
  float lpt = logf(fmaxf(pt, 1e-30f));
  float term = pt * (lpt - logp_self);
  term += __shfl_xor(term, 1); term += __shfl_xor(term, 2); term += __shfl_xor(term, 4);
  float c1 = (e == 0) ? term : 0.f;
  c1 += __shfl_xor(c1, 8); c1 += __shfl_xor(c1, 16); c1 += __shfl_xor(c1, 32);
  if (lane == 0) wred[wv] = c1;

  if (e == rowEidx) out[bg] = outv;  // gating multiplier is exactly 1.0 in fwd

  __syncthreads();
  if (tid == 0) {
    atomicAdd(&accs[8], zred[0] + zred[1] + zred[2] + zred[3]);
    atomicAdd(&accs[9], wred[0] + wred[1] + wred[2] + wred[3]);
  }
  if (tid < 8) atomicAdd(&accs[tid], (float)hist[tid]);
#undef LOADT
#undef COMPUTE
}

// ---------------- kernel 3: finalize scalar ----------------
__global__ void finalize_kernel(const float* __restrict__ accs, float* __restrict__ out) {
  if (threadIdx.x == 0) {
    float fsum = 0.f;
    for (int e = 0; e < 8; ++e) {
      float frac = accs[e] * (1.0f / 16384.0f);
      float f = fmaxf(0.05f - frac, 0.f);
      float c = fmaxf(frac - 0.5f, 0.f);
      fsum += f * f + c * c;
    }
    float aux   = fsum * 0.125f;             // floor_loss + cap_loss (each mean over E)
    float z     = accs[8] * (1.0f / 16384.0f);
    float probe = accs[9] * (1.0f / 16384.0f);
    out[BATCH] = 0.01f * aux + 0.001f * z + 0.01f * probe;
  }
}

extern "C" void kernel_launch(void* const* d_in, const int* in_sizes, int n_in,
                              void* d_out, int out_size, void* d_ws, size_t ws_size,
                              hipStream_t stream) {
  const float* x    = (const float*)d_in[0];
  // d_in[1] = ls_indices: unused (TEACHER_ALPHA == 0)
  const float* psqt = (const float*)d_in[2];
  const float* st   = (const float*)d_in[3];
  const float* rw   = (const float*)d_in[4];
  const float* rb   = (const float*)d_in[5];
  const float* w1   = (const float*)d_in[6];
  const float* b1   = (const float*)d_in[7];
  const float* w2   = (const float*)d_in[8];
  const float* b2   = (const float*)d_in[9];
  const float* w3   = (const float*)d_in[10];
  const float* b3   = (const float*)d_in[11];
  float* out = (float*)d_out;

  unsigned short* w1bf = (unsigned short*)d_ws;                 // 786432 B
  float* accs = (float*)((char*)d_ws + 786432);                 // 16 floats

  cvt_w1_kernel<<<384, 256, 0, stream>>>(w1, w1bf, accs);
  moe_main_kernel<<<512, 256, 0, stream>>>(x, w1bf, b1, w2, b2, w3, b3,
                                           psqt, st, rw, rb, out, accs);
  finalize_kernel<<<1, 1, 0, stream>>>(accs, out);
}

// Round 2
// 333.161 us; speedup vs baseline: 1.1644x; 1.1644x over previous
//
#include <hip/hip_runtime.h>
#include <math.h>

// Sizes (fixed by the reference)
#define BATCH 16384
#define K_DIM 3072

typedef float  f32x4  __attribute__((ext_vector_type(4)));
typedef __bf16 bf16x8 __attribute__((ext_vector_type(8)));
typedef unsigned int u32x2 __attribute__((ext_vector_type(2)));

__device__ __forceinline__ unsigned short f2bf(float f) {
  union { float f; unsigned u; } v; v.f = f;
  unsigned u = v.u + 0x7fffu + ((v.u >> 16) & 1u);   // RNE
  return (unsigned short)(u >> 16);
}

// fp32x8 -> bf16x8, RNE (same rounding as f2bf)
__device__ __forceinline__ bf16x8 cvt8(f32x4 lo, f32x4 hi) {
  bf16x8 r;
  r[0] = (__bf16)lo[0]; r[1] = (__bf16)lo[1]; r[2] = (__bf16)lo[2]; r[3] = (__bf16)lo[3];
  r[4] = (__bf16)hi[0]; r[5] = (__bf16)hi[1]; r[6] = (__bf16)hi[2]; r[7] = (__bf16)hi[3];
  return r;
}

// async global -> LDS DMA, 16 bytes per lane (zero VGPR cost, counts vmcnt)
__device__ __forceinline__ void gld16(const void* g, void* l) {
  __builtin_amdgcn_global_load_lds(
      (const __attribute__((address_space(1))) unsigned int*)g,
      (__attribute__((address_space(3))) unsigned int*)l, 16, 0, 0);
}

// ---------------- kernel 1: w1 fp32 -> bf16 (128*3072 elements) + accs zero ----------------
__global__ void cvt_w1_kernel(const float* __restrict__ w1, unsigned short* __restrict__ o,
                              float* __restrict__ accs) {
  if (blockIdx.x == 0 && threadIdx.x < 16) accs[threadIdx.x] = 0.f;
  int i = blockIdx.x * 256 + threadIdx.x;          // 98304 float4s
  f32x4 v = ((const f32x4*)w1)[i];
  u32x2 p = { (unsigned)f2bf(v.x) | ((unsigned)f2bf(v.y) << 16),
              (unsigned)f2bf(v.z) | ((unsigned)f2bf(v.w) << 16) };
  ((u32x2*)o)[i] = p;
}

// ---------------- kernel 2: fused router + GEMM + MoE epilogue ----------------
// BM=32 rows/block, all 128 outputs, BK=64/iter. 512 blocks x 256 threads.
// K-loop: global_load_lds DMA double-buffer, counted vmcnt(6), raw barriers
// (loads stay in flight across barriers). Source-side XOR swizzle (16B block
// ^ (row&7)) makes all ds_read_b128 in the loop bank-conflict-free.
__global__ __launch_bounds__(256, 2) void moe_main_kernel(
    const float* __restrict__ x, const unsigned short* __restrict__ w1bf,
    const float* __restrict__ b1, const float* __restrict__ w2,
    const float* __restrict__ b2, const float* __restrict__ w3,
    const float* __restrict__ b3, const float* __restrict__ psqt,
    const float* __restrict__ st, const float* __restrict__ rw,
    const float* __restrict__ rb, float* __restrict__ out,
    float* __restrict__ accs) {
  // A0 [0,8192) A1 [8192,16384) B0 [16384,32768) B1 [32768,49152)
  __shared__ __align__(16) unsigned char stage_sm[49152];
  __shared__ __align__(16) float w2s[8 * 964];      // [e][i*32+o], pad-stride 964
  __shared__ int   hist[8];
  __shared__ float zred[4], wred[4];

  const int tid = threadIdx.x;
  const int bm  = blockIdx.x;
  float* Cl = (float*)stage_sm;                     // epilogue overlay (16896 B)

  // ---- stage w2 transposed [e][i*32+o] (conflict-free reads: 964 % 32 == 4) ----
  for (int i = tid; i < 7680; i += 256) {
    int e = i / 960; int r = i - e * 960; int o = r / 30; int ii = r - o * 30;
    w2s[e * 964 + ii * 32 + o] = w2[i];
  }
  if (tid < 8) hist[tid] = 0;
  __syncthreads();

  // ---- wave/lane geometry ----
  const int lane = tid & 63, wv = tid >> 6;
  const int l16 = lane & 15, lq = lane >> 4;
  const int rt = wv & 1;              // row-tile (16 rows)
  const int cb = (wv >> 1) << 2;      // first of 4 col-tiles

  // ---- DMA staging addresses (source-swizzled, LDS linear) ----
  // A: f32 [32 rows][64 k] = 8 KB; slot idx holds 16B-block (idx&15)^(row&7)
  const float* gA[2]; int lA[2];
#pragma unroll
  for (int r = 0; r < 2; ++r) {
    int idx = r * 256 + tid; int row = idx >> 4; int blk = idx & 15;
    gA[r] = x + (size_t)(bm * 32 + row) * K_DIM + ((blk ^ (row & 7)) << 2);
    lA[r] = idx << 4;
  }
  // B: bf16 [128 rows][64 k] = 16 KB; slot idx holds 16B-block (idx&7)^(row&7)
  const unsigned short* gB[4]; int lB[4];
#pragma unroll
  for (int r = 0; r < 4; ++r) {
    int idx = r * 256 + tid; int row = idx >> 3; int blk = idx & 7;
    gB[r] = w1bf + (size_t)row * K_DIM + ((blk ^ (row & 7)) << 3);
    lB[r] = idx << 4;
  }

  // ---- LDS read offsets (same XOR as the writers) ----
  const int arow = rt * 16 + l16;
  int aoff[2], boff[2][4];
#pragma unroll
  for (int ks = 0; ks < 2; ++ks) {
    aoff[ks] = arow * 256 + (((ks * 8 + lq * 2) ^ (arow & 7)) << 4);
#pragma unroll
    for (int cc = 0; cc < 4; ++cc) {
      int o = (cb + cc) * 16 + l16;
      boff[ks][cc] = o * 128 + (((lq + ks * 4) ^ (l16 & 7)) << 4);
    }
  }

#define STAGE(C, KT) do {                                                  \
    unsigned char* ab_ = stage_sm + (C) * 8192;                            \
    unsigned char* bb_ = stage_sm + 16384 + (C) * 16384;                   \
    gld16(gA[0] + (KT) * 64, ab_ + lA[0]);                                 \
    gld16(gA[1] + (KT) * 64, ab_ + lA[1]);                                 \
    gld16(gB[0] + (KT) * 64, bb_ + lB[0]);                                 \
    gld16(gB[1] + (KT) * 64, bb_ + lB[1]);                                 \
    gld16(gB[2] + (KT) * 64, bb_ + lB[2]);                                 \
    gld16(gB[3] + (KT) * 64, bb_ + lB[3]);                                 \
  } while (0)

#define COMPUTE(C) do {                                                    \
    const unsigned char* ab_ = stage_sm + (C) * 8192;                      \
    const unsigned char* bb_ = stage_sm + 16384 + (C) * 16384;             \
    _Pragma("unroll")                                                      \
    for (int ks = 0; ks < 2; ++ks) {                                       \
      f32x4 a0 = *(const f32x4*)(ab_ + aoff[ks]);                          \
      f32x4 a1 = *(const f32x4*)(ab_ + (aoff[ks] ^ 16));                   \
      bf16x8 af = cvt8(a0, a1);                                            \
      _Pragma("unroll")                                                    \
      for (int cc = 0; cc < 4; ++cc) {                                     \
        bf16x8 bfv = *(const bf16x8*)(bb_ + boff[ks][cc]);                 \
        acc[cc] = __builtin_amdgcn_mfma_f32_16x16x32_bf16(af, bfv,         \
                                                          acc[cc], 0,0,0); \
      }                                                                    \
    }                                                                      \
  } while (0)

  // ---- inline router: thread = (row bl, expert e), fp64 for argmax parity ----
  const int bl = tid >> 3, e = tid & 7;
  const int bg = bm * 32 + bl;
  const float* xrow  = x + (size_t)bg * K_DIM;
  const float* rwrow = rw + e * 64;
  double lr = (double)rb[e];
#pragma unroll
  for (int c4 = 0; c4 < 8; ++c4) {
    f32x4 xv = *(const f32x4*)(xrow + c4 * 4);
    f32x4 wvv = *(const f32x4*)(rwrow + c4 * 4);
#pragma unroll
    for (int j = 0; j < 4; ++j) lr = fma((double)xv[j], (double)wvv[j], lr);
  }
#pragma unroll
  for (int c4 = 0; c4 < 8; ++c4) {
    f32x4 xv = *(const f32x4*)(xrow + 1536 + c4 * 4);
    f32x4 wvv = *(const f32x4*)(rwrow + 32 + c4 * 4);
#pragma unroll
    for (int j = 0; j < 4; ++j) lr = fma((double)xv[j], (double)wvv[j], lr);
  }
  // argmax over the 8 expert lanes (first-max-wins, jnp.argmax semantics)
  double mx = lr; int mi = e;
#pragma unroll
  for (int m = 1; m < 8; m <<= 1) {
    double ov = __shfl_xor(mx, m);
    int    oi = __shfl_xor(mi, m);
    if (ov > mx || (ov == mx && oi < mi)) { mx = ov; mi = oi; }
  }
  double ssum = exp(lr - mx);
#pragma unroll
  for (int m = 1; m < 8; m <<= 1) ssum += __shfl_xor(ssum, m);
  const double lse = mx + log(ssum);
  const float  logp_self = (float)(lr - lse);
  const int    rowEidx   = mi;

  if (e == 0) atomicAdd(&hist[rowEidx], 1);
  float zc = (e == 0) ? (float)(lse * lse) : 0.f;
#pragma unroll
  for (int m = 1; m < 64; m <<= 1) zc += __shfl_xor(zc, m);
  if (lane == 0) zred[wv] = zc;

  // ---- K-loop: DMA double-buffer, counted vmcnt, raw barriers ----
  f32x4 acc[4];
#pragma unroll
  for (int cc = 0; cc < 4; ++cc) acc[cc] = (f32x4){0.f, 0.f, 0.f, 0.f};

  asm volatile("s_waitcnt vmcnt(0)" ::: "memory");  // clean vmcnt baseline
  STAGE(0, 0);

#pragma unroll 1
  for (int kt = 0; kt < 46; kt += 2) {
    STAGE(1, kt + 1);
    asm volatile("s_waitcnt vmcnt(6)" ::: "memory");
    __builtin_amdgcn_s_barrier();
    COMPUTE(0);
    __builtin_amdgcn_s_barrier();
    STAGE(0, kt + 2);
    asm volatile("s_waitcnt vmcnt(6)" ::: "memory");
    __builtin_amdgcn_s_barrier();
    COMPUTE(1);
    __builtin_amdgcn_s_barrier();
  }
  // kt = 46, 47 (no further staging after 47)
  STAGE(1, 47);
  asm volatile("s_waitcnt vmcnt(6)" ::: "memory");
  __builtin_amdgcn_s_barrier();
  COMPUTE(0);
  __builtin_amdgcn_s_barrier();
  asm volatile("s_waitcnt vmcnt(0)" ::: "memory");
  __builtin_amdgcn_s_barrier();
  COMPUTE(1);
  __builtin_amdgcn_s_barrier();

  // ---- C -> LDS (overlays staging buffers; all readers finished) ----
#pragma unroll
  for (int cc = 0; cc < 4; ++cc)
#pragma unroll
    for (int r = 0; r < 4; ++r)
      Cl[(rt * 16 + lq * 4 + r) * 132 + (cb + cc) * 16 + l16] = acc[cc][r];
  __syncthreads();

  // ---------------- epilogue: one thread per (sample, expert) ----------------
  float a[16];
  {
    const float* crow = Cl + bl * 132 + e * 16;
    const float* b1p  = b1 + e * 16;
#pragma unroll
    for (int j = 0; j < 16; ++j) a[j] = crow[j] + b1p[j];
  }

  float h[30];
#pragma unroll
  for (int j = 0; j < 15; ++j) {
    float v = a[j];
    h[j]      = fminf(fmaxf(v * v * (255.0f / 256.0f), 0.f), 1.f);
    h[15 + j] = fminf(fmaxf(v, 0.f), 1.f);
  }

  float acc2[32];
  {
    const f32x4* b2v = (const f32x4*)(b2 + e * 32);
#pragma unroll
    for (int o4 = 0; o4 < 8; ++o4) {
      f32x4 t = b2v[o4];
      acc2[o4 * 4 + 0] = t.x; acc2[o4 * 4 + 1] = t.y;
      acc2[o4 * 4 + 2] = t.z; acc2[o4 * 4 + 3] = t.w;
    }
  }
  const f32x4* wrow = (const f32x4*)&w2s[e * 964];
#pragma unroll
  for (int i = 0; i < 30; ++i) {
    float hv = h[i];
#pragma unroll
    for (int o4 = 0; o4 < 8; ++o4) {
      f32x4 wq = wrow[i * 8 + o4];
      acc2[o4 * 4 + 0] += hv * wq.x;
      acc2[o4 * 4 + 1] += hv * wq.y;
      acc2[o4 * 4 + 2] += hv * wq.z;
      acc2[o4 * 4 + 3] += hv * wq.w;
    }
  }

  float outv = b3[e] + a[15];  // b3 + skip
  {
    const f32x4* w3v = (const f32x4*)(w3 + e * 32);
#pragma unroll
    for (int o4 = 0; o4 < 8; ++o4) {
      f32x4 t = w3v[o4];
      outv += fminf(fmaxf(acc2[o4 * 4 + 0], 0.f), 1.f) * t.x;
      outv += fminf(fmaxf(acc2[o4 * 4 + 1], 0.f), 1.f) * t.y;
      outv += fminf(fmaxf(acc2[o4 * 4 + 2], 0.f), 1.f) * t.z;
      outv += fminf(fmaxf(acc2[o4 * 4 + 3], 0.f), 1.f) * t.w;
    }
  }

  // probe softmax over the 8 experts (lanes e=0..7 within each group of 8)
  float eo  = (outv + psqt[bg]) * 600.0f;
  float dd  = eo - st[bg];
  float err = dd * dd;
  float mn = err;
  mn = fminf(mn, __shfl_xor(mn, 1));
  mn = fminf(mn, __shfl_xor(mn, 2));
  mn = fminf(mn, __shfl_xor(mn, 4));
  float wexp = expf(-(err - mn));
  float ss = wexp;
  ss += __shfl_xor(ss, 1); ss += __shfl_xor(ss, 2); ss += __shfl_xor(ss, 4);
  float pt  = wexp / ss;
  float lpt = logf(fmaxf(pt, 1e-30f));
  float term = pt * (lpt - logp_self);
  term += __shfl_xor(term, 1); term += __shfl_xor(term, 2); term += __shfl_xor(term, 4);
  float c1 = (e == 0) ? term : 0.f;
  c1 += __shfl_xor(c1, 8); c1 += __shfl_xor(c1, 16); c1 += __shfl_xor(c1, 32);
  if (lane == 0) wred[wv] = c1;

  if (e == rowEidx) out[bg] = outv;  // gating multiplier is exactly 1.0 in fwd

  __syncthreads();
  if (tid == 0) {
    atomicAdd(&accs[8], zred[0] + zred[1] + zred[2] + zred[3]);
    atomicAdd(&accs[9], wred[0] + wred[1] + wred[2] + wred[3]);
  }
  if (tid < 8) atomicAdd(&accs[tid], (float)hist[tid]);
#undef STAGE
#undef COMPUTE
}

// ---------------- kernel 3: finalize scalar ----------------
__global__ void finalize_kernel(const float* __restrict__ accs, float* __restrict__ out) {
  if (threadIdx.x == 0) {
    float fsum = 0.f;
    for (int e = 0; e < 8; ++e) {
      float frac = accs[e] * (1.0f / 16384.0f);
      float f = fmaxf(0.05f - frac, 0.f);
      float c = fmaxf(frac - 0.5f, 0.f);
      fsum += f * f + c * c;
    }
    float aux   = fsum * 0.125f;             // floor_loss + cap_loss (each mean over E)
    float z     = accs[8] * (1.0f / 16384.0f);
    float probe = accs[9] * (1.0f / 16384.0f);
    out[BATCH] = 0.01f * aux + 0.001f * z + 0.01f * probe;
  }
}

extern "C" void kernel_launch(void* const* d_in, const int* in_sizes, int n_in,
                              void* d_out, int out_size, void* d_ws, size_t ws_size,
                              hipStream_t stream) {
  const float* x    = (const float*)d_in[0];
  // d_in[1] = ls_indices: unused (TEACHER_ALPHA == 0)
  const float* psqt = (const float*)d_in[2];
  const float* st   = (const float*)d_in[3];
  const float* rw   = (const float*)d_in[4];
  const float* rb   = (const float*)d_in[5];
  const float* w1   = (const float*)d_in[6];
  const float* b1   = (const float*)d_in[7];
  const float* w2   = (const float*)d_in[8];
  const float* b2   = (const float*)d_in[9];
  const float* w3   = (const float*)d_in[10];
  const float* b3   = (const float*)d_in[11];
  float* out = (float*)d_out;

  unsigned short* w1bf = (unsigned short*)d_ws;                 // 786432 B
  float* accs = (float*)((char*)d_ws + 786432);                 // 16 floats

  cvt_w1_kernel<<<384, 256, 0, stream>>>(w1, w1bf, accs);
  moe_main_kernel<<<512, 256, 0, stream>>>(x, w1bf, b1, w2, b2, w3, b3,
                                           psqt, st, rw, rb, out, accs);
  finalize_kernel<<<1, 1, 0, stream>>>(accs, out);
}

// Round 3
// 332.286 us; speedup vs baseline: 1.1675x; 1.0026x over previous
//
#include <hip/hip_runtime.h>
#include <math.h>

// Sizes (fixed by the reference)
#define BATCH 16384
#define K_DIM 3072

typedef float  f32x4  __attribute__((ext_vector_type(4)));
typedef __bf16 bf16x8 __attribute__((ext_vector_type(8)));
typedef unsigned int u32x2 __attribute__((ext_vector_type(2)));

__device__ __forceinline__ unsigned short f2bf(float f) {
  union { float f; unsigned u; } v; v.f = f;
  unsigned u = v.u + 0x7fffu + ((v.u >> 16) & 1u);   // RNE
  return (unsigned short)(u >> 16);
}

// fp32x8 -> bf16x8, RNE (same rounding as f2bf)
__device__ __forceinline__ bf16x8 cvt8(f32x4 lo, f32x4 hi) {
  bf16x8 r;
  r[0] = (__bf16)lo[0]; r[1] = (__bf16)lo[1]; r[2] = (__bf16)lo[2]; r[3] = (__bf16)lo[3];
  r[4] = (__bf16)hi[0]; r[5] = (__bf16)hi[1]; r[6] = (__bf16)hi[2]; r[7] = (__bf16)hi[3];
  return r;
}

// async global -> LDS DMA, 16 bytes per lane (zero VGPR cost, counts vmcnt)
__device__ __forceinline__ void gld16(const void* g, void* l) {
  __builtin_amdgcn_global_load_lds(
      (const __attribute__((address_space(1))) unsigned int*)g,
      (__attribute__((address_space(3))) unsigned int*)l, 16, 0, 0);
}

// ---------------- kernel 1: w1 fp32 -> bf16 (128*3072 elements) + accs zero ----------------
__global__ void cvt_w1_kernel(const float* __restrict__ w1, unsigned short* __restrict__ o,
                              float* __restrict__ accs) {
  if (blockIdx.x == 0 && threadIdx.x < 16) accs[threadIdx.x] = 0.f;
  int i = blockIdx.x * 256 + threadIdx.x;          // 98304 float4s
  f32x4 v = ((const f32x4*)w1)[i];
  u32x2 p = { (unsigned)f2bf(v.x) | ((unsigned)f2bf(v.y) << 16),
              (unsigned)f2bf(v.z) | ((unsigned)f2bf(v.w) << 16) };
  ((u32x2*)o)[i] = p;
}

// ---------------- kernel 2: fused router + GEMM + MoE epilogue ----------------
// BM=32 rows/block, all 128 outputs, BK=64/iter. 512 blocks x 256 threads.
// K-loop: global_load_lds DMA into a 3-deep circular buffer, counted
// vmcnt(12) (two stages permanently in flight across barriers). Source-side
// XOR swizzle (16B block ^ (row&7)) keeps ds_read_b128 conflict-free.
// w2 is re-staged into the dead staging LDS after the K-loop (overlay).
__global__ __launch_bounds__(256, 2) void moe_main_kernel(
    const float* __restrict__ x, const unsigned short* __restrict__ w1bf,
    const float* __restrict__ b1, const float* __restrict__ w2,
    const float* __restrict__ b2, const float* __restrict__ w3,
    const float* __restrict__ b3, const float* __restrict__ psqt,
    const float* __restrict__ st, const float* __restrict__ rw,
    const float* __restrict__ rb, float* __restrict__ out,
    float* __restrict__ accs) {
  // buffer c at [c*24576, c*24576+24576): A 8192 B then B 16384 B
  __shared__ __align__(16) unsigned char stage_sm[73728];
  __shared__ int   hist[8];
  __shared__ float zred[4], wred[4];

  const int tid = threadIdx.x;
  const int bm  = blockIdx.x;
  float* Cl  = (float*)stage_sm;                    // epilogue overlay (16896 B)
  float* w2s = (float*)(stage_sm + 17024);          // epilogue overlay (30848 B)

  if (tid < 8) hist[tid] = 0;
  __syncthreads();

  // ---- wave/lane geometry ----
  const int lane = tid & 63, wv = tid >> 6;
  const int l16 = lane & 15, lq = lane >> 4;
  const int rt = wv & 1;              // row-tile (16 rows)
  const int cb = (wv >> 1) << 2;      // first of 4 col-tiles

  // ---- DMA staging addresses (source-swizzled, LDS linear) ----
  // A: f32 [32 rows][64 k] = 8 KB; slot idx holds 16B-block (idx&15)^(row&7)
  const float* gA[2]; int lA[2];
#pragma unroll
  for (int r = 0; r < 2; ++r) {
    int idx = r * 256 + tid; int row = idx >> 4; int blk = idx & 15;
    gA[r] = x + (size_t)(bm * 32 + row) * K_DIM + ((blk ^ (row & 7)) << 2);
    lA[r] = idx << 4;
  }
  // B: bf16 [128 rows][64 k] = 16 KB; slot idx holds 16B-block (idx&7)^(row&7)
  const unsigned short* gB[4]; int lB[4];
#pragma unroll
  for (int r = 0; r < 4; ++r) {
    int idx = r * 256 + tid; int row = idx >> 3; int blk = idx & 7;
    gB[r] = w1bf + (size_t)row * K_DIM + ((blk ^ (row & 7)) << 3);
    lB[r] = idx << 4;
  }

  // ---- LDS read offsets (same XOR as the writers) ----
  const int arow = rt * 16 + l16;
  int aoff[2], boff[2][4];
#pragma unroll
  for (int ks = 0; ks < 2; ++ks) {
    aoff[ks] = arow * 256 + (((ks * 8 + lq * 2) ^ (arow & 7)) << 4);
#pragma unroll
    for (int cc = 0; cc < 4; ++cc) {
      int o = (cb + cc) * 16 + l16;
      boff[ks][cc] = o * 128 + (((lq + ks * 4) ^ (l16 & 7)) << 4);
    }
  }

#define STAGE(C, KT) do {                                                  \
    unsigned char* ab_ = stage_sm + (C) * 24576;                           \
    unsigned char* bb_ = ab_ + 8192;                                       \
    gld16(gA[0] + (KT) * 64, ab_ + lA[0]);                                 \
    gld16(gA[1] + (KT) * 64, ab_ + lA[1]);                                 \
    gld16(gB[0] + (KT) * 64, bb_ + lB[0]);                                 \
    gld16(gB[1] + (KT) * 64, bb_ + lB[1]);                                 \
    gld16(gB[2] + (KT) * 64, bb_ + lB[2]);                                 \
    gld16(gB[3] + (KT) * 64, bb_ + lB[3]);                                 \
  } while (0)

#define COMPUTE(C) do {                                                    \
    const unsigned char* ab_ = stage_sm + (C) * 24576;                     \
    const unsigned char* bb_ = ab_ + 8192;                                 \
    _Pragma("unroll")                                                      \
    for (int ks = 0; ks < 2; ++ks) {                                       \
      f32x4 a0 = *(const f32x4*)(ab_ + aoff[ks]);                          \
      f32x4 a1 = *(const f32x4*)(ab_ + (aoff[ks] ^ 16));                   \
      bf16x8 af = cvt8(a0, a1);                                            \
      _Pragma("unroll")                                                    \
      for (int cc = 0; cc < 4; ++cc) {                                     \
        bf16x8 bfv = *(const bf16x8*)(bb_ + boff[ks][cc]);                 \
        acc[cc] = __builtin_amdgcn_mfma_f32_16x16x32_bf16(af, bfv,         \
                                                          acc[cc], 0,0,0); \
      }                                                                    \
    }                                                                      \
  } while (0)

// one steady-state phase: stage tile T+2, wait tile T (2 stages in flight),
// compute tile T. vmcnt(12) = 2 stages x 6 wave-instructions.
#define PH(C, T) do {                                                      \
    STAGE(((C) + 2) % 3, (T) + 2);                                         \
    asm volatile("s_waitcnt vmcnt(12)" ::: "memory");                      \
    __builtin_amdgcn_s_barrier();                                          \
    COMPUTE(C);                                                            \
    __builtin_amdgcn_s_barrier();                                          \
  } while (0)

  f32x4 acc[4];
#pragma unroll
  for (int cc = 0; cc < 4; ++cc) acc[cc] = (f32x4){0.f, 0.f, 0.f, 0.f};

  // fill tiles 0 and 1; they fly while the router math runs below
  STAGE(0, 0);
  STAGE(1, 1);

  // ---- inline router: thread = (row bl, expert e), fp64 for argmax parity ----
  const int bl = tid >> 3, e = tid & 7;
  const int bg = bm * 32 + bl;
  const float* xrow  = x + (size_t)bg * K_DIM;
  const float* rwrow = rw + e * 64;
  double lr = (double)rb[e];
#pragma unroll
  for (int c4 = 0; c4 < 8; ++c4) {
    f32x4 xv = *(const f32x4*)(xrow + c4 * 4);
    f32x4 wvv = *(const f32x4*)(rwrow + c4 * 4);
#pragma unroll
    for (int j = 0; j < 4; ++j) lr = fma((double)xv[j], (double)wvv[j], lr);
  }
#pragma unroll
  for (int c4 = 0; c4 < 8; ++c4) {
    f32x4 xv = *(const f32x4*)(xrow + 1536 + c4 * 4);
    f32x4 wvv = *(const f32x4*)(rwrow + 32 + c4 * 4);
#pragma unroll
    for (int j = 0; j < 4; ++j) lr = fma((double)xv[j], (double)wvv[j], lr);
  }
  // argmax over the 8 expert lanes (first-max-wins, jnp.argmax semantics)
  double mx = lr; int mi = e;
#pragma unroll
  for (int m = 1; m < 8; m <<= 1) {
    double ov = __shfl_xor(mx, m);
    int    oi = __shfl_xor(mi, m);
    if (ov > mx || (ov == mx && oi < mi)) { mx = ov; mi = oi; }
  }
  double ssum = exp(lr - mx);
#pragma unroll
  for (int m = 1; m < 8; m <<= 1) ssum += __shfl_xor(ssum, m);
  const double lse = mx + log(ssum);
  const float  logp_self = (float)(lr - lse);
  const int    rowEidx   = mi;

  if (e == 0) atomicAdd(&hist[rowEidx], 1);
  float zc = (e == 0) ? (float)(lse * lse) : 0.f;
#pragma unroll
  for (int m = 1; m < 64; m <<= 1) zc += __shfl_xor(zc, m);
  if (lane == 0) zred[wv] = zc;

  // ---- K-loop: 48 tiles, 3-deep circular staging, counted vmcnt ----
#pragma unroll 1
  for (int kt = 0; kt < 45; kt += 3) {
    PH(0, kt);
    PH(1, kt + 1);
    PH(2, kt + 2);
  }
  PH(0, 45);                                        // stages tile 47 into buf 2
  asm volatile("s_waitcnt vmcnt(6)" ::: "memory");  // tile 46 complete
  __builtin_amdgcn_s_barrier();
  COMPUTE(1);
  __builtin_amdgcn_s_barrier();
  asm volatile("s_waitcnt vmcnt(0)" ::: "memory");  // tile 47 complete
  __builtin_amdgcn_s_barrier();
  COMPUTE(2);
  __builtin_amdgcn_s_barrier();

  // ---- C -> LDS + w2 restage (both overlay dead staging buffers) ----
#pragma unroll
  for (int cc = 0; cc < 4; ++cc)
#pragma unroll
    for (int r = 0; r < 4; ++r)
      Cl[(rt * 16 + lq * 4 + r) * 132 + (cb + cc) * 16 + l16] = acc[cc][r];
  for (int i = tid; i < 7680; i += 256) {           // w2 -> [e][i*32+o]
    int ee = i / 960; int rr = i - ee * 960; int o = rr / 30; int ii = rr - o * 30;
    w2s[ee * 964 + ii * 32 + o] = w2[i];
  }
  __syncthreads();

  // ---------------- epilogue: one thread per (sample, expert) ----------------
  float a[16];
  {
    const float* crow = Cl + bl * 132 + e * 16;
    const float* b1p  = b1 + e * 16;
#pragma unroll
    for (int j = 0; j < 16; ++j) a[j] = crow[j] + b1p[j];
  }

  float h[30];
#pragma unroll
  for (int j = 0; j < 15; ++j) {
    float v = a[j];
    h[j]      = fminf(fmaxf(v * v * (255.0f / 256.0f), 0.f), 1.f);
    h[15 + j] = fminf(fmaxf(v, 0.f), 1.f);
  }

  float acc2[32];
  {
    const f32x4* b2v = (const f32x4*)(b2 + e * 32);
#pragma unroll
    for (int o4 = 0; o4 < 8; ++o4) {
      f32x4 t = b2v[o4];
      acc2[o4 * 4 + 0] = t.x; acc2[o4 * 4 + 1] = t.y;
      acc2[o4 * 4 + 2] = t.z; acc2[o4 * 4 + 3] = t.w;
    }
  }
  const f32x4* wrow = (const f32x4*)&w2s[e * 964];
#pragma unroll
  for (int i = 0; i < 30; ++i) {
    float hv = h[i];
#pragma unroll
    for (int o4 = 0; o4 < 8; ++o4) {
      f32x4 wq = wrow[i * 8 + o4];
      acc2[o4 * 4 + 0] += hv * wq.x;
      acc2[o4 * 4 + 1] += hv * wq.y;
      acc2[o4 * 4 + 2] += hv * wq.z;
      acc2[o4 * 4 + 3] += hv * wq.w;
    }
  }

  float outv = b3[e] + a[15];  // b3 + skip
  {
    const f32x4* w3v = (const f32x4*)(w3 + e * 32);
#pragma unroll
    for (int o4 = 0; o4 < 8; ++o4) {
      f32x4 t = w3v[o4];
      outv += fminf(fmaxf(acc2[o4 * 4 + 0], 0.f), 1.f) * t.x;
      outv += fminf(fmaxf(acc2[o4 * 4 + 1], 0.f), 1.f) * t.y;
      outv += fminf(fmaxf(acc2[o4 * 4 + 2], 0.f), 1.f) * t.z;
      outv += fminf(fmaxf(acc2[o4 * 4 + 3], 0.f), 1.f) * t.w;
    }
  }

  // probe softmax over the 8 experts (lanes e=0..7 within each group of 8)
  float eo  = (outv + psqt[bg]) * 600.0f;
  float dd  = eo - st[bg];
  float err = dd * dd;
  float mn = err;
  mn = fminf(mn, __shfl_xor(mn, 1));
  mn = fminf(mn, __shfl_xor(mn, 2));
  mn = fminf(mn, __shfl_xor(mn, 4));
  float wexp = expf(-(err - mn));
  float ss = wexp;
  ss += __shfl_xor(ss, 1); ss += __shfl_xor(ss, 2); ss += __shfl_xor(ss, 4);
  float pt  = wexp / ss;
  float lpt = logf(fmaxf(pt, 1e-30f));
  float term = pt * (lpt - logp_self);
  term += __shfl_xor(term, 1); term += __shfl_xor(term, 2); term += __shfl_xor(term, 4);
  float c1 = (e == 0) ? term : 0.f;
  c1 += __shfl_xor(c1, 8); c1 += __shfl_xor(c1, 16); c1 += __shfl_xor(c1, 32);
  if (lane == 0) wred[wv] = c1;

  if (e == rowEidx) out[bg] = outv;  // gating multiplier is exactly 1.0 in fwd

  __syncthreads();
  if (tid == 0) {
    atomicAdd(&accs[8], zred[0] + zred[1] + zred[2] + zred[3]);
    atomicAdd(&accs[9], wred[0] + wred[1] + wred[2] + wred[3]);
  }
  if (tid < 8) atomicAdd(&accs[tid], (float)hist[tid]);
#undef STAGE
#undef COMPUTE
#undef PH
}

// ---------------- kernel 3: finalize scalar ----------------
__global__ void finalize_kernel(const float* __restrict__ accs, float* __restrict__ out) {
  if (threadIdx.x == 0) {
    float fsum = 0.f;
    for (int e = 0; e < 8; ++e) {
      float frac = accs[e] * (1.0f / 16384.0f);
      float f = fmaxf(0.05f - frac, 0.f);
      float c = fmaxf(frac - 0.5f, 0.f);
      fsum += f * f + c * c;
    }
    float aux   = fsum * 0.125f;             // floor_loss + cap_loss (each mean over E)
    float z     = accs[8] * (1.0f / 16384.0f);
    float probe = accs[9] * (1.0f / 16384.0f);
    out[BATCH] = 0.01f * aux + 0.001f * z + 0.01f * probe;
  }
}

extern "C" void kernel_launch(void* const* d_in, const int* in_sizes, int n_in,
                              void* d_out, int out_size, void* d_ws, size_t ws_size,
                              hipStream_t stream) {
  const float* x    = (const float*)d_in[0];
  // d_in[1] = ls_indices: unused (TEACHER_ALPHA == 0)
  const float* psqt = (const float*)d_in[2];
  const float* st   = (const float*)d_in[3];
  const float* rw   = (const float*)d_in[4];
  const float* rb   = (const float*)d_in[5];
  const float* w1   = (const float*)d_in[6];
  const float* b1   = (const float*)d_in[7];
  const float* w2   = (const float*)d_in[8];
  const float* b2   = (const float*)d_in[9];
  const float* w3   = (const float*)d_in[10];
  const float* b3   = (const float*)d_in[11];
  float* out = (float*)d_out;

  unsigned short* w1bf = (unsigned short*)d_ws;                 // 786432 B
  float* accs = (float*)((char*)d_ws + 786432);                 // 16 floats

  cvt_w1_kernel<<<384, 256, 0, stream>>>(w1, w1bf, accs);
  moe_main_kernel<<<512, 256, 0, stream>>>(x, w1bf, b1, w2, b2, w3, b3,
                                           psqt, st, rw, rb, out, accs);
  finalize_kernel<<<1, 1, 0, stream>>>(accs, out);
}

// Round 5
// 327.423 us; speedup vs baseline: 1.1848x; 1.0149x over previous
//
#include <hip/hip_runtime.h>
#include <math.h>

// Sizes (fixed by the reference)
#define BATCH 16384
#define K_DIM 3072

typedef float  f32x4  __attribute__((ext_vector_type(4)));
typedef __bf16 bf16x8 __attribute__((ext_vector_type(8)));
typedef unsigned int u32x2 __attribute__((ext_vector_type(2)));

__device__ __forceinline__ unsigned short f2bf(float f) {
  union { float f; unsigned u; } v; v.f = f;
  unsigned u = v.u + 0x7fffu + ((v.u >> 16) & 1u);   // RNE
  return (unsigned short)(u >> 16);
}

// fp32x8 -> bf16x8, RNE (same rounding as f2bf)
__device__ __forceinline__ bf16x8 cvt8(f32x4 lo, f32x4 hi) {
  bf16x8 r;
  r[0] = (__bf16)lo[0]; r[1] = (__bf16)lo[1]; r[2] = (__bf16)lo[2]; r[3] = (__bf16)lo[3];
  r[4] = (__bf16)hi[0]; r[5] = (__bf16)hi[1]; r[6] = (__bf16)hi[2]; r[7] = (__bf16)hi[3];
  return r;
}

// async global -> LDS DMA, 16 bytes per lane (zero VGPR cost, counts vmcnt)
__device__ __forceinline__ void gld16(const void* g, void* l) {
  __builtin_amdgcn_global_load_lds(
      (const __attribute__((address_space(1))) unsigned int*)g,
      (__attribute__((address_space(3))) unsigned int*)l, 16, 0, 0);
}

// ---------------- kernel 1: w1 fp32 -> bf16 (128*3072 elements) + accs zero ----------------
__global__ void cvt_w1_kernel(const float* __restrict__ w1, unsigned short* __restrict__ o,
                              float* __restrict__ accs) {
  if (blockIdx.x == 0 && threadIdx.x < 16) accs[threadIdx.x] = 0.f;
  int i = blockIdx.x * 256 + threadIdx.x;          // 98304 float4s
  f32x4 v = ((const f32x4*)w1)[i];
  u32x2 p = { (unsigned)f2bf(v.x) | ((unsigned)f2bf(v.y) << 16),
              (unsigned)f2bf(v.z) | ((unsigned)f2bf(v.w) << 16) };
  ((u32x2*)o)[i] = p;
}

// ---------------- kernel 2: fused router + GEMM + MoE epilogue ----------------
// 512 blocks x 512 threads. Waves 4-7 = producers (DMA staging + counted vmcnt
// waits only; all memory latency lands here). Waves 0-3 = consumers (router +
// ds_read/MFMA; their stream contains NO global_load_lds, so no vmcnt waits of
// any kind land on the compute path). ONE shared phase loop: every s_barrier
// is in converged control flow (role split is a wave-uniform branch inside the
// phase), so barrier counts cannot mismatch. 3-deep circular staging buffer;
// producer finishes tile p+1 (vmcnt(6)) before the barrier of phase p+1 where
// consumers read it. Source-side XOR swizzle keeps ds_read_b128 conflict-free.
__global__ __launch_bounds__(512, 4) void moe_main_kernel(
    const float* __restrict__ x, const unsigned short* __restrict__ w1bf,
    const float* __restrict__ b1, const float* __restrict__ w2,
    const float* __restrict__ b2, const float* __restrict__ w3,
    const float* __restrict__ b3, const float* __restrict__ psqt,
    const float* __restrict__ st, const float* __restrict__ rw,
    const float* __restrict__ rb, float* __restrict__ out,
    float* __restrict__ accs) {
  // buffer c at [c*24576, (c+1)*24576): A 8192 B then B 16384 B
  __shared__ __align__(16) unsigned char stage_sm[73728];
  __shared__ int   hist[8];
  __shared__ float zred[4], wred[4];

  const int tid = threadIdx.x;
  const int bm  = blockIdx.x;
  float* Cl  = (float*)stage_sm;                    // epilogue overlay (16896 B)
  float* w2s = (float*)(stage_sm + 17024);          // epilogue overlay (30848 B)

  if (tid < 8) hist[tid] = 0;
  __syncthreads();

  const int lane = tid & 63;
  const bool isProd = (tid >= 256);

  // per-role state (declared in common scope; filled only by the owning role)
  const float* gA[2]; int lA[2];
  const unsigned short* gB[4]; int lB[4];
  int aoff[2], boff[2][4];
  f32x4 acc[4];
  float logp_self = 0.f;
  int   rowEidx   = 0;

#define STAGE(C, KT) do {                                                  \
    unsigned char* ab_ = stage_sm + (C) * 24576;                           \
    unsigned char* bb_ = ab_ + 8192;                                       \
    gld16(gA[0] + (KT) * 64, ab_ + lA[0]);                                 \
    gld16(gA[1] + (KT) * 64, ab_ + lA[1]);                                 \
    gld16(gB[0] + (KT) * 64, bb_ + lB[0]);                                 \
    gld16(gB[1] + (KT) * 64, bb_ + lB[1]);                                 \
    gld16(gB[2] + (KT) * 64, bb_ + lB[2]);                                 \
    gld16(gB[3] + (KT) * 64, bb_ + lB[3]);                                 \
  } while (0)

#define COMPUTE(C) do {                                                    \
    const unsigned char* ab_ = stage_sm + (C) * 24576;                     \
    const unsigned char* bb_ = ab_ + 8192;                                 \
    _Pragma("unroll")                                                      \
    for (int ks = 0; ks < 2; ++ks) {                                       \
      f32x4 a0 = *(const f32x4*)(ab_ + aoff[ks]);                          \
      f32x4 a1 = *(const f32x4*)(ab_ + (aoff[ks] ^ 16));                   \
      bf16x8 af = cvt8(a0, a1);                                            \
      _Pragma("unroll")                                                    \
      for (int cc = 0; cc < 4; ++cc) {                                     \
        bf16x8 bfv = *(const bf16x8*)(bb_ + boff[ks][cc]);                 \
        acc[cc] = __builtin_amdgcn_mfma_f32_16x16x32_bf16(af, bfv,         \
                                                          acc[cc], 0,0,0); \
      }                                                                    \
    }                                                                      \
  } while (0)

  if (isProd) {
    // ---- producer setup + pipeline fill (overlaps consumer router) ----
    const int ptid = tid & 255;
    // A: f32 [32 rows][64 k] = 8 KB; slot idx holds 16B-block (idx&15)^(row&7)
#pragma unroll
    for (int r = 0; r < 2; ++r) {
      int idx = r * 256 + ptid; int row = idx >> 4; int blk = idx & 15;
      gA[r] = x + (size_t)(bm * 32 + row) * K_DIM + ((blk ^ (row & 7)) << 2);
      lA[r] = idx << 4;
    }
    // B: bf16 [128 rows][64 k] = 16 KB; slot idx holds 16B-block (idx&7)^(row&7)
#pragma unroll
    for (int r = 0; r < 4; ++r) {
      int idx = r * 256 + ptid; int row = idx >> 3; int blk = idx & 7;
      gB[r] = w1bf + (size_t)row * K_DIM + ((blk ^ (row & 7)) << 3);
      lB[r] = idx << 4;
    }
    STAGE(0, 0);
    STAGE(1, 1);
    asm volatile("s_waitcnt vmcnt(6)" ::: "memory");   // tile 0 complete
  } else {
    // ---- consumer setup ----
    const int cwv = tid >> 6;
    const int l16 = lane & 15, lq = lane >> 4;
    const int rt = cwv & 1;             // row-tile (16 rows)
    const int cb = (cwv >> 1) << 2;     // first of 4 col-tiles
    const int arow = rt * 16 + l16;
#pragma unroll
    for (int ks = 0; ks < 2; ++ks) {
      aoff[ks] = arow * 256 + (((ks * 8 + lq * 2) ^ (arow & 7)) << 4);
#pragma unroll
      for (int cc = 0; cc < 4; ++cc) {
        int o = (cb + cc) * 16 + l16;
        boff[ks][cc] = o * 128 + (((lq + ks * 4) ^ (l16 & 7)) << 4);
      }
    }
#pragma unroll
    for (int cc = 0; cc < 4; ++cc) acc[cc] = (f32x4){0.f, 0.f, 0.f, 0.f};

    // ---- inline router: thread = (row bl, expert e), fp64 for argmax parity ----
    const int bl = tid >> 3, e = tid & 7;
    const int bg = bm * 32 + bl;
    const float* xrow  = x + (size_t)bg * K_DIM;
    const float* rwrow = rw + e * 64;
    double lr = (double)rb[e];
#pragma unroll
    for (int c4 = 0; c4 < 8; ++c4) {
      f32x4 xv  = *(const f32x4*)(xrow + c4 * 4);
      f32x4 wvv = *(const f32x4*)(rwrow + c4 * 4);
#pragma unroll
      for (int j = 0; j < 4; ++j) lr = fma((double)xv[j], (double)wvv[j], lr);
    }
#pragma unroll
    for (int c4 = 0; c4 < 8; ++c4) {
      f32x4 xv  = *(const f32x4*)(xrow + 1536 + c4 * 4);
      f32x4 wvv = *(const f32x4*)(rwrow + 32 + c4 * 4);
#pragma unroll
      for (int j = 0; j < 4; ++j) lr = fma((double)xv[j], (double)wvv[j], lr);
    }
    // argmax over the 8 expert lanes (first-max-wins, jnp.argmax semantics)
    double mx = lr; int mi = e;
#pragma unroll
    for (int m = 1; m < 8; m <<= 1) {
      double ov = __shfl_xor(mx, m);
      int    oi = __shfl_xor(mi, m);
      if (ov > mx || (ov == mx && oi < mi)) { mx = ov; mi = oi; }
    }
    double ssum = exp(lr - mx);
#pragma unroll
    for (int m = 1; m < 8; m <<= 1) ssum += __shfl_xor(ssum, m);
    const double lse = mx + log(ssum);
    logp_self = (float)(lr - lse);
    rowEidx   = mi;

    if (e == 0) atomicAdd(&hist[rowEidx], 1);
    float zc = (e == 0) ? (float)(lse * lse) : 0.f;
#pragma unroll
    for (int m = 1; m < 64; m <<= 1) zc += __shfl_xor(zc, m);
    if (lane == 0) zred[cwv] = zc;
  }

  // ---- 48 shared phases; consumer computes tile p (buffer p%3) in phase p;
  //      producer stages tile p+2 and retires tile p+1 before phase p+1.
#pragma unroll 1
  for (int base = 0; base < 45; base += 3) {
    __builtin_amdgcn_s_barrier();
    if (isProd) { STAGE(2, base + 2); asm volatile("s_waitcnt vmcnt(6)" ::: "memory"); }
    else        COMPUTE(0);
    __builtin_amdgcn_s_barrier();
    if (isProd) { STAGE(0, base + 3); asm volatile("s_waitcnt vmcnt(6)" ::: "memory"); }
    else        COMPUTE(1);
    __builtin_amdgcn_s_barrier();
    if (isProd) { STAGE(1, base + 4); asm volatile("s_waitcnt vmcnt(6)" ::: "memory"); }
    else        COMPUTE(2);
  }
  __builtin_amdgcn_s_barrier();                      // phase 45
  if (isProd) { STAGE(2, 47); asm volatile("s_waitcnt vmcnt(6)" ::: "memory"); }
  else        COMPUTE(0);
  __builtin_amdgcn_s_barrier();                      // phase 46
  if (isProd) { asm volatile("s_waitcnt vmcnt(0)" ::: "memory"); }
  else        COMPUTE(1);
  __builtin_amdgcn_s_barrier();                      // phase 47
  if (!isProd) COMPUTE(2);

  // ---- join: C -> LDS (consumers), w2 restage (all threads) ----
  __syncthreads();                                   // all K-loop LDS reads done
  if (!isProd) {
    const int cwv = tid >> 6;
    const int l16 = lane & 15, lq = lane >> 4;
    const int rt = cwv & 1, cb = (cwv >> 1) << 2;
#pragma unroll
    for (int cc = 0; cc < 4; ++cc)
#pragma unroll
      for (int r = 0; r < 4; ++r)
        Cl[(rt * 16 + lq * 4 + r) * 132 + (cb + cc) * 16 + l16] = acc[cc][r];
  }
  for (int i = tid; i < 7680; i += 512) {           // w2 -> [e][i*32+o]
    int ee = i / 960; int rr = i - ee * 960; int o = rr / 30; int ii = rr - o * 30;
    w2s[ee * 964 + ii * 32 + o] = w2[i];
  }
  __syncthreads();

  // ---------------- epilogue: one thread per (sample, expert) ----------------
  if (tid < 256) {
    const int bl = tid >> 3, e = tid & 7;
    const int bg = bm * 32 + bl;

    float a[16];
    {
      const float* crow = Cl + bl * 132 + e * 16;
      const float* b1p  = b1 + e * 16;
#pragma unroll
      for (int j = 0; j < 16; ++j) a[j] = crow[j] + b1p[j];
    }

    float h[30];
#pragma unroll
    for (int j = 0; j < 15; ++j) {
      float v = a[j];
      h[j]      = fminf(fmaxf(v * v * (255.0f / 256.0f), 0.f), 1.f);
      h[15 + j] = fminf(fmaxf(v, 0.f), 1.f);
    }

    float acc2[32];
    {
      const f32x4* b2v = (const f32x4*)(b2 + e * 32);
#pragma unroll
      for (int o4 = 0; o4 < 8; ++o4) {
        f32x4 t = b2v[o4];
        acc2[o4 * 4 + 0] = t.x; acc2[o4 * 4 + 1] = t.y;
        acc2[o4 * 4 + 2] = t.z; acc2[o4 * 4 + 3] = t.w;
      }
    }
    const f32x4* wrow = (const f32x4*)&w2s[e * 964];
#pragma unroll
    for (int i = 0; i < 30; ++i) {
      float hv = h[i];
#pragma unroll
      for (int o4 = 0; o4 < 8; ++o4) {
        f32x4 wq = wrow[i * 8 + o4];
        acc2[o4 * 4 + 0] += hv * wq.x;
        acc2[o4 * 4 + 1] += hv * wq.y;
        acc2[o4 * 4 + 2] += hv * wq.z;
        acc2[o4 * 4 + 3] += hv * wq.w;
      }
    }

    float outv = b3[e] + a[15];  // b3 + skip
    {
      const f32x4* w3v = (const f32x4*)(w3 + e * 32);
#pragma unroll
      for (int o4 = 0; o4 < 8; ++o4) {
        f32x4 t = w3v[o4];
        outv += fminf(fmaxf(acc2[o4 * 4 + 0], 0.f), 1.f) * t.x;
        outv += fminf(fmaxf(acc2[o4 * 4 + 1], 0.f), 1.f) * t.y;
        outv += fminf(fmaxf(acc2[o4 * 4 + 2], 0.f), 1.f) * t.z;
        outv += fminf(fmaxf(acc2[o4 * 4 + 3], 0.f), 1.f) * t.w;
      }
    }

    // probe softmax over the 8 experts (lanes e=0..7 within each group of 8)
    float eo  = (outv + psqt[bg]) * 600.0f;
    float dd  = eo - st[bg];
    float err = dd * dd;
    float mn = err;
    mn = fminf(mn, __shfl_xor(mn, 1));
    mn = fminf(mn, __shfl_xor(mn, 2));
    mn = fminf(mn, __shfl_xor(mn, 4));
    float wexp = expf(-(err - mn));
    float ss = wexp;
    ss += __shfl_xor(ss, 1); ss += __shfl_xor(ss, 2); ss += __shfl_xor(ss, 4);
    float pt  = wexp / ss;
    float lpt = logf(fmaxf(pt, 1e-30f));
    float term = pt * (lpt - logp_self);
    term += __shfl_xor(term, 1); term += __shfl_xor(term, 2); term += __shfl_xor(term, 4);
    float c1 = (e == 0) ? term : 0.f;
    c1 += __shfl_xor(c1, 8); c1 += __shfl_xor(c1, 16); c1 += __shfl_xor(c1, 32);
    if (lane == 0) wred[tid >> 6] = c1;

    if (e == rowEidx) out[bg] = outv;  // gating multiplier is exactly 1.0 in fwd
  }

  __syncthreads();
  if (tid == 0) {
    atomicAdd(&accs[8], zred[0] + zred[1] + zred[2] + zred[3]);
    atomicAdd(&accs[9], wred[0] + wred[1] + wred[2] + wred[3]);
  }
  if (tid < 8) atomicAdd(&accs[tid], (float)hist[tid]);
#undef STAGE
#undef COMPUTE
}

// ---------------- kernel 3: finalize scalar ----------------
__global__ void finalize_kernel(const float* __restrict__ accs, float* __restrict__ out) {
  if (threadIdx.x == 0) {
    float fsum = 0.f;
    for (int e = 0; e < 8; ++e) {
      float frac = accs[e] * (1.0f / 16384.0f);
      float f = fmaxf(0.05f - frac, 0.f);
      float c = fmaxf(frac - 0.5f, 0.f);
      fsum += f * f + c * c;
    }
    float aux   = fsum * 0.125f;             // floor_loss + cap_loss (each mean over E)
    float z     = accs[8] * (1.0f / 16384.0f);
    float probe = accs[9] * (1.0f / 16384.0f);
    out[BATCH] = 0.01f * aux + 0.001f * z + 0.01f * probe;
  }
}

extern "C" void kernel_launch(void* const* d_in, const int* in_sizes, int n_in,
                              void* d_out, int out_size, void* d_ws, size_t ws_size,
                              hipStream_t stream) {
  const float* x    = (const float*)d_in[0];
  // d_in[1] = ls_indices: unused (TEACHER_ALPHA == 0)
  const float* psqt = (const float*)d_in[2];
  const float* st   = (const float*)d_in[3];
  const float* rw   = (const float*)d_in[4];
  const float* rb   = (const float*)d_in[5];
  const float* w1   = (const float*)d_in[6];
  const float* b1   = (const float*)d_in[7];
  const float* w2   = (const float*)d_in[8];
  const float* b2   = (const float*)d_in[9];
  const float* w3   = (const float*)d_in[10];
  const float* b3   = (const float*)d_in[11];
  float* out = (float*)d_out;

  unsigned short* w1bf = (unsigned short*)d_ws;                 // 786432 B
  float* accs = (float*)((char*)d_ws + 786432);                 // 16 floats

  cvt_w1_kernel<<<384, 256, 0, stream>>>(w1, w1bf, accs);
  moe_main_kernel<<<512, 512, 0, stream>>>(x, w1bf, b1, w2, b2, w3, b3,
                                           psqt, st, rw, rb, out, accs);
  finalize_kernel<<<1, 1, 0, stream>>>(accs, out);
}